// Round 5
// baseline (1124.039 us; speedup 1.0000x reference)
//
#include <hip/hip_runtime.h>

typedef __attribute__((ext_vector_type(8))) short short8_t;
typedef __attribute__((ext_vector_type(4))) float f32x4_t;
typedef __attribute__((ext_vector_type(4))) unsigned int u32x4_t;

#define DDIM  128
#define BM    32
#define ROWB  1024            // bytes per LDS row: 256 f32 (h_l | h_r)
#define TILEB (BM * ROWB)     // 32 KB per buffer
#define NBLK  512             // persistent blocks (2/CU)

__device__ __forceinline__ unsigned short f2bf(float x) {
  union { float f; unsigned u; } v; v.f = x;
  unsigned r = v.u + 0x7FFFu + ((v.u >> 16) & 1u);   // RNE
  return (unsigned short)(r >> 16);
}

__device__ __forceinline__ float sigf(float x) {
  return __builtin_amdgcn_rcpf(1.0f + __expf(-x));
}
__device__ __forceinline__ float tanh_fast(float x) {
  return 2.0f * __builtin_amdgcn_rcpf(1.0f + __expf(-2.0f * x)) - 1.0f;
}

// pack two f32 bit-patterns into one u32 of two bf16 (truncate; h-side only)
__device__ __forceinline__ unsigned pk2(unsigned lo, unsigned hi) {
  return (hi & 0xFFFF0000u) | (lo >> 16);
}

__device__ __forceinline__ void gload_lds16(const float* gp, char* lp) {
  __builtin_amdgcn_global_load_lds(
      (const __attribute__((address_space(1))) void*)gp,
      (__attribute__((address_space(3))) void*)lp, 16, 0, 0);
}

// Wt[c][k] = bf16(W[k][c]);  W:[256][640] f32, Wt:[640][256] bf16 (RNE)
__global__ void convert_w_kernel(const float* __restrict__ W,
                                 unsigned short* __restrict__ Wt,
                                 int twoD, int fiveD) {
  const int c = blockIdx.x;
  const int k = threadIdx.x;
  Wt[c * twoD + k] = f2bf(W[k * fiveD + c]);
}

__global__ __launch_bounds__(512, 4)
void treelstm_fused_kernel(const float* __restrict__ h_bot,
                           const float* __restrict__ c_bot,
                           const float* __restrict__ h_buf,
                           const float* __restrict__ c_buf,
                           const int* __restrict__ idx_bl,
                           const int* __restrict__ idx_pl,
                           const int* __restrict__ idx_br,
                           const int* __restrict__ idx_pr,
                           const float* __restrict__ bias,
                           const unsigned short* __restrict__ Wt,
                           float* __restrict__ out,
                           int K, int M, int ntiles) {
  __shared__ __align__(128) char A_lds[2 * TILEB];   // 64 KB double-buffered f32 tile

  const int tid  = threadIdx.x;
  const int w    = tid >> 6;          // wave 0..7 -> owns d-block w (for all 5 gates)
  const int lane = tid & 63;
  const int l16  = lane & 15;
  const int lq   = lane >> 4;         // 0..3
  const int d0   = w * 16 + lq * 4;
  const int w4   = w * 4;             // first staged row of this wave

  // LDS-read swizzle bases: byte = row*1024 + kk*128 + off0 (+16 via off1)
  const int off0 = ((lq * 2) ^ (l16 & 7)) << 4;
  const int off1 = off0 ^ 16;

  float* const out_h = out;
  float* const out_c = out + (size_t)M * DDIM;

  const int stride = gridDim.x;
  int t = blockIdx.x;
  if (t >= ntiles) return;

  // bias fragments (tile-invariant; acc is initialized from these)
  f32x4_t bs[5];
  #pragma unroll
  for (int g = 0; g < 5; ++g)
    bs[g] = *(const f32x4_t*)(bias + g * DDIM + d0);

#define LOAD_IQS(tt, dst)                                                  \
  { _Pragma("unroll")                                                      \
    for (int q = 0; q < 4; ++q) {                                          \
      int m = (tt) * BM + w4 + q; if (m >= M) m = M - 1;                   \
      const int* p;                                                        \
      if (lane < 32) p = (m < K) ? (idx_bl + m) : (idx_pl + (m - K));      \
      else           p = (m < K) ? (idx_br + m) : (idx_pr + (m - K));      \
      dst[q] = *p;                                                         \
    } }

#define LOAD_ICS(tt, dl, dr)                                               \
  { _Pragma("unroll")                                                      \
    for (int mt = 0; mt < 2; ++mt) {                                       \
      int m = (tt) * BM + mt * 16 + l16; if (m >= M) m = M - 1;            \
      dl[mt] = (m < K) ? idx_bl[m] : idx_pl[m - K];                        \
      dr[mt] = (m < K) ? idx_br[m] : idx_pr[m - K];                        \
    } }

  // stage tile tt's gathered h rows (f32) into LDS buffer bufp.
  // wave w stages rows w*4..w*4+3. lane l loads 16B chunk ((l&31)^key) of
  // half (l>>5); LDS dest is lane-linear (global-side pre-swizzle =>
  // bank-conflict-free swizzled reads with read key l16&7 == row&7).
#define STAGE(tt, bufp, iqs)                                               \
  { _Pragma("unroll")                                                      \
    for (int q = 0; q < 4; ++q) {                                          \
      int m = (tt) * BM + w4 + q; if (m >= M) m = M - 1;                   \
      const int key = (w4 + q) & 7;                                        \
      const float* hb = (m < K) ? h_bot : h_buf;                           \
      const float* gp = hb + (size_t)iqs[q] * DDIM + (((lane & 31) ^ key) << 2); \
      char* lp = (bufp) + (w4 + q) * ROWB;                                 \
      gload_lds16(gp, lp);                                                 \
    } }

#define GATHER_C(tt, icl, icr, cl, cr)                                     \
  { _Pragma("unroll")                                                      \
    for (int mt = 0; mt < 2; ++mt) {                                       \
      int m = (tt) * BM + mt * 16 + l16; if (m >= M) m = M - 1;            \
      const float* cbl = (m < K) ? c_bot : c_buf;                          \
      cl[mt] = *(const f32x4_t*)(cbl + (size_t)icl[mt] * DDIM + d0);       \
      cr[mt] = *(const f32x4_t*)(cbl + (size_t)icr[mt] * DDIM + d0);       \
    } }

  int iqs_cur[4];
  int icl_cur[2], icr_cur[2], icl_nxt[2], icr_nxt[2];

  // ---- prologue: stage tile t into buf0; prefetch idx for t+stride ----
  LOAD_IQS(t, iqs_cur);
  LOAD_ICS(t, icl_cur, icr_cur);
  STAGE(t, A_lds, iqs_cur);
  if (t + stride < ntiles) LOAD_IQS(t + stride, iqs_cur);
  __syncthreads();     // drains gl_lds (buf0 ready) + idx prefetch

  int cur = 0;
  for (;;) {
    const int tn = t + stride;
    const bool more = (tn < ntiles);
    char* const bufc = A_lds + cur * TILEB;
    char* const bufn = A_lds + (cur ^ 1) * TILEB;

    // (1) issue next tile's gather-stage (async, zero VGPR held)
    if (more) STAGE(tn, bufn, iqs_cur);

    // (2) issue this tile's c-gathers (consumed post-GEMM)
    f32x4_t cl[2], cr[2];
    GATHER_C(t, icl_cur, icr_cur, cl, cr);

    // (3) prefetch idx for t+2*stride (stage) and t+stride (c)
    if (tn + stride < ntiles) LOAD_IQS(tn + stride, iqs_cur);
    if (more) LOAD_ICS(tn, icl_nxt, icr_nxt);

    // (4) GEMM over buf[cur]: 2 m-tiles x 5 gates x K=256
    f32x4_t acc[2][5];
    #pragma unroll
    for (int mt = 0; mt < 2; ++mt)
      #pragma unroll
      for (int g = 0; g < 5; ++g)
        acc[mt][g] = bs[g];

    #pragma unroll
    for (int kk = 0; kk < 8; ++kk) {
      short8_t hf[2];
      #pragma unroll
      for (int mt = 0; mt < 2; ++mt) {
        const char* rb = bufc + (mt * 16 + l16) * ROWB + kk * 128;
        u32x4_t r0 = *(const u32x4_t*)(rb + off0);
        u32x4_t r1 = *(const u32x4_t*)(rb + off1);
        union { unsigned u[4]; short8_t s; } pv;
        pv.u[0] = pk2(r0.x, r0.y); pv.u[1] = pk2(r0.z, r0.w);
        pv.u[2] = pk2(r1.x, r1.y); pv.u[3] = pk2(r1.z, r1.w);
        hf[mt] = pv.s;
      }
      #pragma unroll
      for (int g = 0; g < 5; ++g) {
        const short8_t wf = *(const short8_t*)(
            Wt + (size_t)(g * DDIM + w * 16 + l16) * 256 + lq * 8 + kk * 32);
        #pragma unroll
        for (int mt = 0; mt < 2; ++mt)
          acc[mt][g] = __builtin_amdgcn_mfma_f32_16x16x32_bf16(
              wf, hf[mt], acc[mt][g], 0, 0, 0);
      }
    }

    // (5) epilogue: LSTM cell + stores (bias already in acc)
    #pragma unroll
    for (int mt = 0; mt < 2; ++mt) {
      const int m = t * BM + mt * 16 + l16;
      if (m < M) {
        f32x4_t hv4, cv4;
        #pragma unroll
        for (int j = 0; j < 4; ++j) {
          const float gi = acc[mt][0][j];
          const float go = acc[mt][1][j];
          const float gu = acc[mt][2][j];
          const float gl = acc[mt][3][j];
          const float gr = acc[mt][4][j];
          const float cn = sigf(gi) * tanh_fast(gu)
                         + sigf(gl) * cl[mt][j] + sigf(gr) * cr[mt][j];
          const float hn = sigf(go) * tanh_fast(cn);
          cv4[j] = cn; hv4[j] = hn;
        }
        const size_t off = (size_t)m * DDIM + d0;
        *(f32x4_t*)(out_h + off) = hv4;
        *(f32x4_t*)(out_c + off) = cv4;
      }
    }

    if (!more) break;
    icl_cur[0] = icl_nxt[0]; icl_cur[1] = icl_nxt[1];
    icr_cur[0] = icr_nxt[0]; icr_cur[1] = icr_nxt[1];
    __syncthreads();   // drains stage gl_lds -> buf[cur^1] ready; read-safe flip
    cur ^= 1;
    t = tn;
  }
#undef LOAD_IQS
#undef LOAD_ICS
#undef STAGE
#undef GATHER_C
}

extern "C" void kernel_launch(void* const* d_in, const int* in_sizes, int n_in,
                              void* d_out, int out_size, void* d_ws, size_t ws_size,
                              hipStream_t stream) {
  const float* h_bot  = (const float*)d_in[0];
  const float* c_bot  = (const float*)d_in[1];
  const float* h_buf  = (const float*)d_in[2];
  const float* c_buf  = (const float*)d_in[3];
  const int*   idx_bl = (const int*)d_in[4];
  const int*   idx_pl = (const int*)d_in[5];
  const int*   idx_br = (const int*)d_in[6];
  const int*   idx_pr = (const int*)d_in[7];
  const float* W      = (const float*)d_in[8];
  const float* bias   = (const float*)d_in[9];

  const int K = in_sizes[4];
  const int M = 2 * K;
  const int fiveD = in_sizes[9];               // 640
  const int twoD  = in_sizes[8] / fiveD;       // 256

  unsigned short* Wt = (unsigned short*)d_ws;  // [640][256] bf16 = 320 KB

  hipLaunchKernelGGL(convert_w_kernel, dim3(fiveD), dim3(twoD), 0, stream,
                     W, Wt, twoD, fiveD);

  const int ntiles = (M + BM - 1) / BM;
  hipLaunchKernelGGL(treelstm_fused_kernel, dim3(NBLK), dim3(512), 0, stream,
                     h_bot, c_bot, h_buf, c_buf,
                     idx_bl, idx_pl, idx_br, idx_pr,
                     bias, Wt, (float*)d_out, K, M, ntiles);
}

// Round 6
// 739.784 us; speedup vs baseline: 1.5194x; 1.5194x over previous
//
#include <hip/hip_runtime.h>

typedef __attribute__((ext_vector_type(8))) short short8_t;
typedef __attribute__((ext_vector_type(4))) float f32x4_t;

#define DDIM 128
#define BM   32
#define LDA  264   // ushort elems per LDS row: 528B stride, 16B aligned, 4-bank shift/row

__device__ __forceinline__ unsigned short f2bf(float x) {
  union { float f; unsigned u; } v; v.f = x;
  unsigned r = v.u + 0x7FFFu + ((v.u >> 16) & 1u);   // RNE
  return (unsigned short)(r >> 16);
}

__device__ __forceinline__ float sigf(float x) {
  return __builtin_amdgcn_rcpf(1.0f + __expf(-x));
}
__device__ __forceinline__ float tanh_fast(float x) {
  return 2.0f * __builtin_amdgcn_rcpf(1.0f + __expf(-2.0f * x)) - 1.0f;
}

// Wt[c][k] = bf16(W[k][c]);  W:[256][640] f32, Wt:[640][256] bf16 (RNE)
__global__ void convert_w_kernel(const float* __restrict__ W,
                                 unsigned short* __restrict__ Wt,
                                 int twoD, int fiveD) {
  const int c = blockIdx.x;
  const int k = threadIdx.x;
  Wt[c * twoD + k] = f2bf(W[k * fiveD + c]);
}

__global__ __launch_bounds__(256, 6)
void treelstm_fused_kernel(const float* __restrict__ h_bot,
                           const float* __restrict__ c_bot,
                           const float* __restrict__ h_buf,
                           const float* __restrict__ c_buf,
                           const int* __restrict__ idx_bl,
                           const int* __restrict__ idx_pl,
                           const int* __restrict__ idx_br,
                           const int* __restrict__ idx_pr,
                           const float* __restrict__ bias,
                           const unsigned short* __restrict__ Wt,
                           float* __restrict__ out,
                           int K, int M) {
  __shared__ __align__(16) unsigned short A_lds[BM * LDA];   // 16.5 KB

  const int tid   = threadIdx.x;
  const int mbase = blockIdx.x * BM;

  const int wave = tid >> 6;          // 0..3
  const int lane = tid & 63;
  const int l16  = lane & 15;
  const int lq   = lane >> 4;         // 0..3

  // ---- preload epilogue indices (overlaps staging latency) ----
  int il[2], ir[2];
  #pragma unroll
  for (int mt = 0; mt < 2; ++mt) {
    int m = mbase + mt * 16 + l16; if (m >= M) m = M - 1;
    il[mt] = (m < K) ? idx_bl[m] : idx_pl[m - K];
    ir[mt] = (m < K) ? idx_br[m] : idx_pr[m - K];
  }

  // ---- stage gathered h rows -> LDS bf16 (A[m][0:128]=h_l, [128:256]=h_r) ----
  {
    const int r    = tid >> 3;        // 0..31 local row
    const int seg  = tid & 7;
    const int half = seg >> 2;        // 0: h_l, 1: h_r
    const int cs   = seg & 3;
    int ms = mbase + r; if (ms >= M) ms = M - 1;

    int hidx; const float* hsrc;
    if (half == 0) {
      if (ms < K) { hidx = idx_bl[ms];     hsrc = h_bot; }
      else        { hidx = idx_pl[ms - K]; hsrc = h_buf; }
    } else {
      if (ms < K) { hidx = idx_br[ms];     hsrc = h_bot; }
      else        { hidx = idx_pr[ms - K]; hsrc = h_buf; }
    }
    const float4* s4 = (const float4*)(hsrc + (size_t)hidx * DDIM);
    unsigned short* dst = &A_lds[r * LDA + half * DDIM];
    #pragma unroll
    for (int q = 0; q < 8; ++q) {
      const int f4i = cs + 4 * q;            // 0..31 within the half
      float4 v = s4[f4i];
      ushort4 u;
      u.x = f2bf(v.x); u.y = f2bf(v.y); u.z = f2bf(v.z); u.w = f2bf(v.w);
      *(ushort4*)(dst + f4i * 4) = u;
    }
  }
  __syncthreads();

  float* const out_h = out;
  float* const out_c = out + (size_t)M * DDIM;

  // ---- two GEMM passes per wave: d-block = wave + 4*p ----
  #pragma unroll
  for (int p = 0; p < 2; ++p) {
    const int dblk = wave + 4 * p;
    const int d0   = dblk * 16 + lq * 4;

    f32x4_t acc[2][5];
    #pragma unroll
    for (int mt = 0; mt < 2; ++mt)
      #pragma unroll
      for (int g = 0; g < 5; ++g) {
        f32x4_t z = {0.0f, 0.0f, 0.0f, 0.0f};
        acc[mt][g] = z;
      }

    const unsigned short* wb = Wt + (size_t)(dblk * 16 + l16) * 256 + lq * 8;
    const int ab = l16 * LDA + lq * 8;

    #pragma unroll
    for (int kk = 0; kk < 8; ++kk) {
      const int k0 = kk * 32;
      short8_t hf[2];
      #pragma unroll
      for (int mt = 0; mt < 2; ++mt)
        hf[mt] = *(const short8_t*)(&A_lds[ab + mt * (16 * LDA) + k0]);
      #pragma unroll
      for (int g = 0; g < 5; ++g) {
        const short8_t wf = *(const short8_t*)(wb + (size_t)g * (128 * 256) + k0);
        #pragma unroll
        for (int mt = 0; mt < 2; ++mt)
          acc[mt][g] = __builtin_amdgcn_mfma_f32_16x16x32_bf16(
              wf, hf[mt], acc[mt][g], 0, 0, 0);
      }
    }

    // ---- epilogue for this pass: bias + c-gather + LSTM cell + stores ----
    f32x4_t bs[5];
    #pragma unroll
    for (int g = 0; g < 5; ++g)
      bs[g] = *(const f32x4_t*)(bias + g * DDIM + d0);

    #pragma unroll
    for (int mt = 0; mt < 2; ++mt) {
      const int m = mbase + mt * 16 + l16;
      if (m < M) {
        const float* cls = (m < K) ? c_bot : c_buf;
        const f32x4_t clv = *(const f32x4_t*)(cls + (size_t)il[mt] * DDIM + d0);
        const f32x4_t crv = *(const f32x4_t*)(cls + (size_t)ir[mt] * DDIM + d0);
        f32x4_t hv4, cv4;
        #pragma unroll
        for (int j = 0; j < 4; ++j) {
          const float gi = acc[mt][0][j] + bs[0][j];
          const float go = acc[mt][1][j] + bs[1][j];
          const float gu = acc[mt][2][j] + bs[2][j];
          const float gl = acc[mt][3][j] + bs[3][j];
          const float gr = acc[mt][4][j] + bs[4][j];
          const float cn = sigf(gi) * tanh_fast(gu)
                         + sigf(gl) * clv[j] + sigf(gr) * crv[j];
          const float hn = sigf(go) * tanh_fast(cn);
          cv4[j] = cn; hv4[j] = hn;
        }
        const size_t off = (size_t)m * DDIM + d0;
        *(f32x4_t*)(out_h + off) = hv4;
        *(f32x4_t*)(out_c + off) = cv4;
      }
    }
  }
}

extern "C" void kernel_launch(void* const* d_in, const int* in_sizes, int n_in,
                              void* d_out, int out_size, void* d_ws, size_t ws_size,
                              hipStream_t stream) {
  const float* h_bot  = (const float*)d_in[0];
  const float* c_bot  = (const float*)d_in[1];
  const float* h_buf  = (const float*)d_in[2];
  const float* c_buf  = (const float*)d_in[3];
  const int*   idx_bl = (const int*)d_in[4];
  const int*   idx_pl = (const int*)d_in[5];
  const int*   idx_br = (const int*)d_in[6];
  const int*   idx_pr = (const int*)d_in[7];
  const float* W      = (const float*)d_in[8];
  const float* bias   = (const float*)d_in[9];

  const int K = in_sizes[4];
  const int M = 2 * K;
  const int fiveD = in_sizes[9];               // 640
  const int twoD  = in_sizes[8] / fiveD;       // 256

  unsigned short* Wt = (unsigned short*)d_ws;  // [640][256] bf16 = 320 KB

  hipLaunchKernelGGL(convert_w_kernel, dim3(fiveD), dim3(twoD), 0, stream,
                     W, Wt, twoD, fiveD);

  const int grid = (M + BM - 1) / BM;
  hipLaunchKernelGGL(treelstm_fused_kernel, dim3(grid), dim3(256), 0, stream,
                     h_bot, c_bot, h_buf, c_buf,
                     idx_bl, idx_pl, idx_br, idx_pr,
                     bias, Wt, (float*)d_out, K, M);
}

// Round 7
// 628.700 us; speedup vs baseline: 1.7879x; 1.1767x over previous
//
#include <hip/hip_runtime.h>

typedef __attribute__((ext_vector_type(8))) short short8_t;
typedef __attribute__((ext_vector_type(4))) float f32x4_t;

#define DDIM 128
#define BM   32
#define LDA  264   // ushort elems per LDS row: 528B stride, 16B aligned, 2-way max conflict

__device__ __forceinline__ unsigned short f2bf(float x) {
  union { float f; unsigned u; } v; v.f = x;
  unsigned r = v.u + 0x7FFFu + ((v.u >> 16) & 1u);   // RNE
  return (unsigned short)(r >> 16);
}

__device__ __forceinline__ float sigf(float x) {
  return __builtin_amdgcn_rcpf(1.0f + __expf(-x));
}
__device__ __forceinline__ float tanh_fast(float x) {
  return 2.0f * __builtin_amdgcn_rcpf(1.0f + __expf(-2.0f * x)) - 1.0f;
}

// Wt[c][k] = bf16(W[k][c]);  W:[256][640] f32, Wt:[640][256] bf16 (RNE)
__global__ void convert_w_kernel(const float* __restrict__ W,
                                 unsigned short* __restrict__ Wt,
                                 int twoD, int fiveD) {
  const int c = blockIdx.x;
  const int k = threadIdx.x;
  Wt[c * twoD + k] = f2bf(W[k * fiveD + c]);
}

__global__ __launch_bounds__(256, 4)
void treelstm_fused_kernel(const float* __restrict__ h_bot,
                           const float* __restrict__ c_bot,
                           const float* __restrict__ h_buf,
                           const float* __restrict__ c_buf,
                           const int* __restrict__ idx_bl,
                           const int* __restrict__ idx_pl,
                           const int* __restrict__ idx_br,
                           const int* __restrict__ idx_pr,
                           const float* __restrict__ bias,
                           const unsigned short* __restrict__ Wt,
                           float* __restrict__ out,
                           int K, int M) {
  __shared__ __align__(16) unsigned short A_lds[BM * LDA];   // 16.5 KB

  const int tid   = threadIdx.x;
  const int mbase = blockIdx.x * BM;

  const int wave = tid >> 6;          // 0..3
  const int lane = tid & 63;
  const int l16  = lane & 15;
  const int lq   = lane >> 4;         // 0..3

  // ---- preload epilogue indices (latency overlaps staging below) ----
  int il[2], ir[2];
  #pragma unroll
  for (int mt = 0; mt < 2; ++mt) {
    int m = mbase + mt * 16 + l16; if (m >= M) m = M - 1;
    il[mt] = (m < K) ? idx_bl[m] : idx_pl[m - K];
    ir[mt] = (m < K) ? idx_br[m] : idx_pr[m - K];
  }

  // ---- stage gathered h rows -> LDS bf16 (A[m][0:128]=h_l, [128:256]=h_r) ----
  {
    const int r    = tid >> 3;        // 0..31 local row
    const int seg  = tid & 7;
    const int half = seg >> 2;        // 0: h_l, 1: h_r
    const int cs   = seg & 3;
    int ms = mbase + r; if (ms >= M) ms = M - 1;

    int hidx; const float* hsrc;
    if (half == 0) {
      if (ms < K) { hidx = idx_bl[ms];     hsrc = h_bot; }
      else        { hidx = idx_pl[ms - K]; hsrc = h_buf; }
    } else {
      if (ms < K) { hidx = idx_br[ms];     hsrc = h_bot; }
      else        { hidx = idx_pr[ms - K]; hsrc = h_buf; }
    }
    const float4* s4 = (const float4*)(hsrc + (size_t)hidx * DDIM);
    unsigned short* dst = &A_lds[r * LDA + half * DDIM];
    #pragma unroll
    for (int q = 0; q < 8; ++q) {
      const int f4i = cs + 4 * q;            // 0..31 within the half
      float4 v = s4[f4i];
      ushort4 u;
      u.x = f2bf(v.x); u.y = f2bf(v.y); u.z = f2bf(v.z); u.w = f2bf(v.w);
      *(ushort4*)(dst + f4i * 4) = u;
    }
  }
  __syncthreads();

  float* const out_h = out;
  float* const out_c = out + (size_t)M * DDIM;

  // ---- c-gathers for BOTH passes issued up front; GEMM hides their latency ----
  const int d0a = wave * 16 + lq * 4;          // pass 0 d-offset
  const int d0b = d0a + 64;                    // pass 1 d-offset
  f32x4_t cl0[2], cr0[2], cl1[2], cr1[2];
  #pragma unroll
  for (int mt = 0; mt < 2; ++mt) {
    const int m = mbase + mt * 16 + l16;
    const float* cb = (m < K) ? c_bot : c_buf;
    const float* pl = cb + (size_t)il[mt] * DDIM;
    const float* pr = cb + (size_t)ir[mt] * DDIM;
    cl0[mt] = *(const f32x4_t*)(pl + d0a);
    cr0[mt] = *(const f32x4_t*)(pr + d0a);
    cl1[mt] = *(const f32x4_t*)(pl + d0b);
    cr1[mt] = *(const f32x4_t*)(pr + d0b);
  }

#define GEMM_PASS(DBLK, D0, CL, CR)                                          \
  {                                                                          \
    f32x4_t acc[2][5];                                                       \
    _Pragma("unroll")                                                        \
    for (int mt = 0; mt < 2; ++mt)                                           \
      _Pragma("unroll")                                                      \
      for (int g = 0; g < 5; ++g) {                                          \
        f32x4_t z = {0.0f, 0.0f, 0.0f, 0.0f};                                \
        acc[mt][g] = z;                                                      \
      }                                                                      \
    const unsigned short* wb = Wt + (size_t)((DBLK) * 16 + l16) * 256 + lq * 8; \
    const int ab = l16 * LDA + lq * 8;                                       \
    _Pragma("unroll")                                                        \
    for (int kk = 0; kk < 8; ++kk) {                                         \
      const int k0 = kk * 32;                                                \
      short8_t hf[2];                                                        \
      _Pragma("unroll")                                                      \
      for (int mt = 0; mt < 2; ++mt)                                         \
        hf[mt] = *(const short8_t*)(&A_lds[ab + mt * (16 * LDA) + k0]);      \
      _Pragma("unroll")                                                      \
      for (int g = 0; g < 5; ++g) {                                          \
        const short8_t wf =                                                  \
            *(const short8_t*)(wb + (size_t)g * (128 * 256) + k0);           \
        _Pragma("unroll")                                                    \
        for (int mt = 0; mt < 2; ++mt)                                       \
          acc[mt][g] = __builtin_amdgcn_mfma_f32_16x16x32_bf16(              \
              wf, hf[mt], acc[mt][g], 0, 0, 0);                              \
      }                                                                      \
    }                                                                        \
    f32x4_t bs[5];                                                           \
    _Pragma("unroll")                                                        \
    for (int g = 0; g < 5; ++g)                                              \
      bs[g] = *(const f32x4_t*)(bias + g * DDIM + (D0));                     \
    _Pragma("unroll")                                                        \
    for (int mt = 0; mt < 2; ++mt) {                                         \
      const int m = mbase + mt * 16 + l16;                                   \
      if (m < M) {                                                           \
        f32x4_t hv4, cv4;                                                    \
        _Pragma("unroll")                                                    \
        for (int j = 0; j < 4; ++j) {                                        \
          const float gi = acc[mt][0][j] + bs[0][j];                         \
          const float go = acc[mt][1][j] + bs[1][j];                         \
          const float gu = acc[mt][2][j] + bs[2][j];                         \
          const float gl = acc[mt][3][j] + bs[3][j];                         \
          const float gr = acc[mt][4][j] + bs[4][j];                         \
          const float cn = sigf(gi) * tanh_fast(gu)                          \
                         + sigf(gl) * CL[mt][j] + sigf(gr) * CR[mt][j];      \
          const float hn = sigf(go) * tanh_fast(cn);                         \
          cv4[j] = cn; hv4[j] = hn;                                          \
        }                                                                    \
        const size_t off = (size_t)m * DDIM + (D0);                          \
        __builtin_nontemporal_store(hv4, (f32x4_t*)(out_h + off));           \
        __builtin_nontemporal_store(cv4, (f32x4_t*)(out_c + off));           \
      }                                                                      \
    }                                                                        \
  }

  GEMM_PASS(wave,     d0a, cl0, cr0)
  GEMM_PASS(wave + 4, d0b, cl1, cr1)
#undef GEMM_PASS
}

extern "C" void kernel_launch(void* const* d_in, const int* in_sizes, int n_in,
                              void* d_out, int out_size, void* d_ws, size_t ws_size,
                              hipStream_t stream) {
  const float* h_bot  = (const float*)d_in[0];
  const float* c_bot  = (const float*)d_in[1];
  const float* h_buf  = (const float*)d_in[2];
  const float* c_buf  = (const float*)d_in[3];
  const int*   idx_bl = (const int*)d_in[4];
  const int*   idx_pl = (const int*)d_in[5];
  const int*   idx_br = (const int*)d_in[6];
  const int*   idx_pr = (const int*)d_in[7];
  const float* W      = (const float*)d_in[8];
  const float* bias   = (const float*)d_in[9];

  const int K = in_sizes[4];
  const int M = 2 * K;
  const int fiveD = in_sizes[9];               // 640
  const int twoD  = in_sizes[8] / fiveD;       // 256

  unsigned short* Wt = (unsigned short*)d_ws;  // [640][256] bf16 = 320 KB

  hipLaunchKernelGGL(convert_w_kernel, dim3(fiveD), dim3(twoD), 0, stream,
                     W, Wt, twoD, fiveD);

  const int grid = (M + BM - 1) / BM;
  hipLaunchKernelGGL(treelstm_fused_kernel, dim3(grid), dim3(256), 0, stream,
                     h_bot, c_bot, h_buf, c_buf,
                     idx_bl, idx_pl, idx_br, idx_pr,
                     bias, Wt, (float*)d_out, K, M);
}